// Round 1
// 224.008 us; speedup vs baseline: 1.4032x; 1.4032x over previous
//
#include <hip/hip_runtime.h>
#include <stdint.h>

#define HID  128
#define N1   512
#define NCAT 1024
#define NTB  48      // edges per tile in the fused kernel

typedef _Float16 f16;
typedef __attribute__((ext_vector_type(8))) _Float16 f16x8;
typedef __attribute__((ext_vector_type(4))) _Float16 f16x4;
typedef __attribute__((ext_vector_type(8))) short   short8;
typedef __attribute__((ext_vector_type(4))) float   floatx4;
typedef __attribute__((ext_vector_type(2))) float   floatx2;
typedef __attribute__((ext_vector_type(8))) __bf16  bf16x8;

static __device__ __forceinline__ short f2bf(float x) {
  uint32_t u = __builtin_bit_cast(uint32_t, x);
  uint32_t r = (u + 0x7FFFu + ((u >> 16) & 1u)) >> 16;
  return (short)r;
}
static __device__ __forceinline__ float bf2f(short s) {
  uint32_t u = ((uint32_t)(uint16_t)s) << 16;
  return __builtin_bit_cast(float, u);
}

// async global->LDS, 16B per lane. Global source address is per-lane
// (scatter/gather OK); LDS dest is wave-uniform base + lane*16.
static __device__ __forceinline__ void gload16(const f16* g, f16* l) {
  __builtin_amdgcn_global_load_lds(
      (const __attribute__((address_space(1))) unsigned int*)g,
      (__attribute__((address_space(3))) unsigned int*)l, 16, 0, 0);
}

// ---------------- tier-1 (fused fp16 MFMA) ----------------

// prep: A' = relu(feats) as f16 (n_nodes,128); BT2[n][k] = W1[k][n] f16,
// n in [0,512), k in [0,256) (K = concat dim: k<128 -> u-features).
__global__ __launch_bounds__(256) void prep_all(
    const float* __restrict__ feats, const float* __restrict__ W1,
    f16* __restrict__ A, f16* __restrict__ BT2, int total4) {
  int idx = blockIdx.x * 256 + threadIdx.x;
  if (idx < total4) {
    floatx4 f = *(const floatx4*)(feats + (size_t)idx * 4);
    f16x4 o;
#pragma unroll
    for (int j = 0; j < 4; ++j) o[j] = (f16)fmaxf(f[j], 0.f);
    *(f16x4*)(A + (size_t)idx * 4) = o;
    return;
  }
  int w = idx - total4;
  if (w < N1 * 256) {
    int n = w >> 8;
    int k = w & 255;
    BT2[w] = (f16)W1[k * N1 + n];
  }
}

// Fused edge MLP: per 48-edge tile, gather A'[u]/A'[v] rows into LDS
// (double-buffered, swizzled via pre-swizzled global source), MFMA
// (K=256, N=512 across 8 waves, W1^T register-resident), then
// relu(.+b1)@W2+b2 in f32 registers with a cross-wave LDS reduce.
// GH intermediate (205 MB write + 1.02 GB gather) is eliminated.
__global__ __launch_bounds__(512, 2) void fused_kernel(
    const f16* __restrict__ A,      // (n_nodes,128) relu'd f16
    const f16* __restrict__ BT2,    // (512,256) f16 = W1^T
    const float* __restrict__ b1,   // (512,)
    const float* __restrict__ W2,   // (512,2)
    const float* __restrict__ b2,   // (2,)
    const int* __restrict__ edges,  // (2, n_edges) int32
    float* __restrict__ out,        // (n_edges,2)
    int n_edges, int ntiles) {
  __shared__ f16 AU[2][NTB][HID];       // 24 KB  (u-feature half, K 0..127)
  __shared__ f16 AV[2][NTB][HID];       // 24 KB  (v-feature half, K 128..255)
  __shared__ float   part[8][NTB][2];   // 3 KB   cross-wave partials
  __shared__ float   b1s[N1];           // 2 KB
  __shared__ floatx2 w2s[N1];           // 4 KB   (W2[n][0],W2[n][1]) pairs

  const int tid  = threadIdx.x;
  const int wave = tid >> 6;
  const int lane = tid & 63;
  const int quad = lane >> 4;
  const int l16  = lane & 15;
  const int n0w  = wave << 6;           // this wave's 64-col N slice

  if (tid < N1) {
    b1s[tid] = b1[tid];
    w2s[tid] = *(const floatx2*)(W2 + 2 * tid);
  }

  // Persistent B fragments: rows n0w..n0w+63 of BT2, all K=256.
  // 32 x f16x8 = 128 VGPRs/lane. Same fragment convention as the verified
  // gemm7: row <-> l16, k <-> quad*8 + kk*32 (+0..7).
  f16x8 bfr[4][8];
#pragma unroll
  for (int nn = 0; nn < 4; ++nn) {
    const f16* bp = BT2 + (size_t)(n0w + nn * 16 + l16) * 256 + quad * 8;
#pragma unroll
    for (int kk = 0; kk < 8; ++kk) bfr[nn][kk] = *(const f16x8*)(bp + kk * 32);
  }

  // Gather geometry: 24 calls of 4 rows (64 lanes x 16B = 1KB each);
  // wave w issues calls j = 3w..3w+2.  j<12 -> AU rows 4j.., else AV.
  const int j0   = wave * 3;
  const int rsub = lane >> 4;   // row within the 4-row call

  int idr[3];
  auto load_idx = [&](int t) {
#pragma unroll
    for (int c = 0; c < 3; ++c) {
      int j = j0 + c;
      int side = (j >= 12) ? 1 : 0;
      int r = ((j - side * 12) << 2) + rsub;
      int e = t * NTB + r;
      if (e >= n_edges) e = n_edges - 1;       // clamp (also covers t >= ntiles prefetch)
      idr[c] = edges[side * n_edges + e];
    }
  };
  // XOR-swizzle (T2): LDS[r][chunk c] holds global 16B chunk c ^ (r&15);
  // achieved by pre-swizzling the per-lane GLOBAL address (m173 pattern) so
  // the LDS dest stays linear for global_load_lds.
  auto issue_gather = [&](int bb) {
#pragma unroll
    for (int c = 0; c < 3; ++c) {
      int j = j0 + c;
      int side = (j >= 12) ? 1 : 0;
      int r0 = (j - side * 12) << 2;
      int r  = r0 + rsub;
      const f16* src = A + ((size_t)idr[c] << 7) + (((lane & 15) ^ (r & 15)) << 3);
      f16* dst = side ? &AV[bb][r0][0] : &AU[bb][r0][0];
      gload16(src, dst);
    }
  };

  const int NB = gridDim.x;
  const int t0 = blockIdx.x;
  if (t0 < ntiles) {
    load_idx(t0);
    issue_gather(0);
    load_idx(t0 + NB);     // indices for next tile (values used next iter)
  }

  int bb = 0;
  for (int t = t0; t < ntiles; t += NB) {
    // Drains vmcnt: gathers for tile t (and idx prefetch) are complete.
    // Also orders previous tile's part-reads before this tile's part-writes.
    __syncthreads();

    if (t + NB < ntiles) {
      issue_gather(bb ^ 1);          // next tile's gathers fly under compute
      load_idx(t + 2 * NB);
    }

    floatx4 acc[3][4];
#pragma unroll
    for (int mt = 0; mt < 3; ++mt)
#pragma unroll
      for (int nn = 0; nn < 4; ++nn) acc[mt][nn] = (floatx4){0.f, 0.f, 0.f, 0.f};

    const f16* au = &AU[bb][0][0];
    const f16* av = &AV[bb][0][0];
#pragma unroll
    for (int kk = 0; kk < 8; ++kk) {
      const f16* base = (kk < 4) ? au : av;
      // logical 16B chunk ck = (kk&3)*4 + quad; swizzled column = ck ^ (m&15)
      const int coff = (((((kk & 3) << 2) + quad)) ^ l16) << 3;
      f16x8 a0 = *(const f16x8*)(base + (0 * 16 + l16) * HID + coff);
      f16x8 a1 = *(const f16x8*)(base + (1 * 16 + l16) * HID + coff);
      f16x8 a2 = *(const f16x8*)(base + (2 * 16 + l16) * HID + coff);
#pragma unroll
      for (int nn = 0; nn < 4; ++nn) {
        acc[0][nn] = __builtin_amdgcn_mfma_f32_16x16x32_f16(bfr[nn][kk], a0, acc[0][nn], 0, 0, 0);
        acc[1][nn] = __builtin_amdgcn_mfma_f32_16x16x32_f16(bfr[nn][kk], a1, acc[1][nn], 0, 0, 0);
        acc[2][nn] = __builtin_amdgcn_mfma_f32_16x16x32_f16(bfr[nn][kk], a2, acc[2][nn], 0, 0, 0);
      }
    }

    // Epilogue: lane holds hidden[m = mt*16+l16][n = n0w+nn*16+quad*4+r].
    // relu(.+b1) then dot with W2 columns, all f32.
    float s0[3] = {0.f, 0.f, 0.f};
    float s1[3] = {0.f, 0.f, 0.f};
#pragma unroll
    for (int nn = 0; nn < 4; ++nn) {
      const int nb = n0w + nn * 16 + (quad << 2);
      const floatx4 bv = *(const floatx4*)&b1s[nb];   // LDS broadcast reads
      const floatx2 wa = w2s[nb + 0];
      const floatx2 wb = w2s[nb + 1];
      const floatx2 wc = w2s[nb + 2];
      const floatx2 wd = w2s[nb + 3];
#pragma unroll
      for (int mt = 0; mt < 3; ++mt) {
        float p0 = fmaxf(acc[mt][nn][0] + bv[0], 0.f);
        float p1 = fmaxf(acc[mt][nn][1] + bv[1], 0.f);
        float p2 = fmaxf(acc[mt][nn][2] + bv[2], 0.f);
        float p3 = fmaxf(acc[mt][nn][3] + bv[3], 0.f);
        s0[mt] += p0 * wa[0] + p1 * wb[0] + p2 * wc[0] + p3 * wd[0];
        s1[mt] += p0 * wa[1] + p1 * wb[1] + p2 * wc[1] + p3 * wd[1];
      }
    }
#pragma unroll
    for (int mt = 0; mt < 3; ++mt) {
      float a0 = s0[mt] + __shfl_xor(s0[mt], 16);
      a0 += __shfl_xor(a0, 32);
      float a1 = s1[mt] + __shfl_xor(s1[mt], 16);
      a1 += __shfl_xor(a1, 32);
      if (quad == 0) {
        floatx2 o = {a0, a1};
        *(floatx2*)&part[wave][mt * 16 + l16][0] = o;
      }
    }
    __syncthreads();   // part writes visible (next-tile gathers long done by now)
    if (tid < 2 * NTB) {
      const int m  = tid >> 1;
      const int jj = tid & 1;
      float s = part[0][m][jj] + part[1][m][jj] + part[2][m][jj] + part[3][m][jj]
              + part[4][m][jj] + part[5][m][jj] + part[6][m][jj] + part[7][m][jj];
      const int e = t * NTB + m;
      if (e < n_edges) out[2 * (size_t)e + jj] = s + b2[jj];
    }
    bb ^= 1;
  }
}

// ---------------- tier-2 fallback (bf16, GH materialized) ----------------

__global__ __launch_bounds__(256) void conv_bt_bf(
    const float* __restrict__ W1, short* __restrict__ BT) {
  int idx = blockIdx.x * 256 + threadIdx.x;
  int n = idx >> 7;
  int k = idx & 127;
  float w = (n < N1) ? W1[k * N1 + n] : W1[(k + HID) * N1 + (n - N1)];
  BT[idx] = f2bf(w);
}

__global__ __launch_bounds__(256) void gemm_bf(
    const float* __restrict__ feats, const short* __restrict__ BT,
    short* __restrict__ GH, int n_nodes) {
  const int wave = threadIdx.x >> 6;
  const int lane = threadIdx.x & 63;
  const int quad = lane >> 4;
  const int l16  = lane & 15;
  const int row0 = blockIdx.x * 64 + wave * 16;
  const int n0   = blockIdx.y * 128;
  const int m  = row0 + l16;
  const int mc = (m < n_nodes) ? m : (n_nodes - 1);
  const float* arow = feats + (size_t)mc * HID;
  floatx4 acc[8];
#pragma unroll
  for (int i = 0; i < 8; ++i) acc[i] = (floatx4){0.f, 0.f, 0.f, 0.f};
#pragma unroll
  for (int kk = 0; kk < 4; ++kk) {
    const int kbase = kk * 32 + quad * 8;
    floatx4 a0 = *(const floatx4*)(arow + kbase);
    floatx4 a1 = *(const floatx4*)(arow + kbase + 4);
    short8 af;
#pragma unroll
    for (int j = 0; j < 4; ++j) { float x = a0[j]; af[j] = f2bf(x > 0.f ? x : 0.f); }
#pragma unroll
    for (int j = 0; j < 4; ++j) { float x = a1[j]; af[4 + j] = f2bf(x > 0.f ? x : 0.f); }
    bf16x8 afrag = __builtin_bit_cast(bf16x8, af);
#pragma unroll
    for (int nn = 0; nn < 8; ++nn) {
      const int n = n0 + nn * 16 + l16;
      short8 bs = *(const short8*)(BT + (size_t)n * HID + kbase);
      acc[nn] = __builtin_amdgcn_mfma_f32_16x16x32_bf16(
          afrag, __builtin_bit_cast(bf16x8, bs), acc[nn], 0, 0, 0);
    }
  }
#pragma unroll
  for (int nn = 0; nn < 8; ++nn) {
    const int col = n0 + nn * 16 + l16;
#pragma unroll
    for (int r = 0; r < 4; ++r) {
      const int row = row0 + quad * 4 + r;
      if (row < n_nodes) GH[(size_t)row * NCAT + col] = f2bf(acc[nn][r]);
    }
  }
}

__global__ __launch_bounds__(256) void edge2_bf(
    const short* __restrict__ GH, const int* __restrict__ edges,
    const float* __restrict__ b1, const float* __restrict__ W2,
    const float* __restrict__ b2, float* __restrict__ out, int n_edges) {
  const int wave = threadIdx.x >> 6;
  const int lane = threadIdx.x & 63;
  const int w = blockIdx.x * 4 + wave;
  const int e0 = 2 * w;
  if (e0 >= n_edges) return;
  const bool has1 = (e0 + 1 < n_edges);
  const int j0 = lane * 8;
  const int u0 = edges[e0];
  const int v0 = edges[n_edges + e0];
  const int u1 = has1 ? edges[e0 + 1] : u0;
  const int v1 = has1 ? edges[n_edges + e0 + 1] : v0;
  short8 g0 = *(const short8*)(GH + (size_t)u0 * NCAT + j0);
  short8 h0 = *(const short8*)(GH + (size_t)v0 * NCAT + N1 + j0);
  short8 g1 = *(const short8*)(GH + (size_t)u1 * NCAT + j0);
  short8 h1 = *(const short8*)(GH + (size_t)v1 * NCAT + N1 + j0);
  float bv[8];
  {
    floatx4 t0 = *(const floatx4*)(b1 + j0);
    floatx4 t1 = *(const floatx4*)(b1 + j0 + 4);
#pragma unroll
    for (int j = 0; j < 4; ++j) { bv[j] = t0[j]; bv[4 + j] = t1[j]; }
  }
  float wv[16];
#pragma unroll
  for (int q = 0; q < 4; ++q) {
    floatx4 tt = *(const floatx4*)(W2 + (size_t)j0 * 2 + q * 4);
#pragma unroll
    for (int j = 0; j < 4; ++j) wv[q * 4 + j] = tt[j];
  }
  float s00 = 0.f, s01 = 0.f, s10 = 0.f, s11 = 0.f;
#pragma unroll
  for (int j = 0; j < 8; ++j) {
    float p0 = bf2f(g0[j]) + bf2f(h0[j]) + bv[j];
    p0 = p0 > 0.f ? p0 : 0.f;
    s00 += p0 * wv[2 * j];
    s01 += p0 * wv[2 * j + 1];
    float p1 = bf2f(g1[j]) + bf2f(h1[j]) + bv[j];
    p1 = p1 > 0.f ? p1 : 0.f;
    s10 += p1 * wv[2 * j];
    s11 += p1 * wv[2 * j + 1];
  }
#pragma unroll
  for (int off = 32; off > 0; off >>= 1) {
    s00 += __shfl_down(s00, off, 64);
    s01 += __shfl_down(s01, off, 64);
    s10 += __shfl_down(s10, off, 64);
    s11 += __shfl_down(s11, off, 64);
  }
  if (lane == 0) {
    out[2 * (size_t)e0]     = s00 + b2[0];
    out[2 * (size_t)e0 + 1] = s01 + b2[1];
    if (has1) {
      out[2 * (size_t)e0 + 2] = s10 + b2[0];
      out[2 * (size_t)e0 + 3] = s11 + b2[1];
    }
  }
}

// ---------------- tier-3 fallback: direct fp32 ----------------
__global__ __launch_bounds__(256) void slow_kernel(
    const float* __restrict__ feats, const int* __restrict__ edges,
    const float* __restrict__ W1, const float* __restrict__ b1,
    const float* __restrict__ W2, const float* __restrict__ b2,
    float* __restrict__ out, int n_edges) {
  const int wave = threadIdx.x >> 6;
  const int lane = threadIdx.x & 63;
  const int edge = blockIdx.x * 4 + wave;
  if (edge >= n_edges) return;
  const int u = edges[edge];
  const int v = edges[n_edges + edge];
  float f[4];
  f[0] = feats[(size_t)u * HID + lane];
  f[1] = feats[(size_t)u * HID + 64 + lane];
  f[2] = feats[(size_t)v * HID + lane];
  f[3] = feats[(size_t)v * HID + 64 + lane];
#pragma unroll
  for (int i = 0; i < 4; ++i) f[i] = f[i] > 0.f ? f[i] : 0.f;
  const int j0 = lane * 8;
  float acc[8];
#pragma unroll
  for (int j = 0; j < 8; ++j) acc[j] = 0.f;
#pragma unroll
  for (int seg = 0; seg < 4; ++seg) {
    float fs = f[seg];
    for (int k2 = 0; k2 < 64; ++k2) {
      float fk = __shfl(fs, k2, 64);
      const float* wr = W1 + (size_t)(seg * 64 + k2) * N1 + j0;
#pragma unroll
      for (int j = 0; j < 8; ++j) acc[j] += fk * wr[j];
    }
  }
  float s0 = 0.f, s1 = 0.f;
#pragma unroll
  for (int j = 0; j < 8; ++j) {
    float p = acc[j] + b1[j0 + j];
    p = p > 0.f ? p : 0.f;
    s0 += p * W2[(size_t)(j0 + j) * 2];
    s1 += p * W2[(size_t)(j0 + j) * 2 + 1];
  }
#pragma unroll
  for (int off = 32; off > 0; off >>= 1) {
    s0 += __shfl_down(s0, off, 64);
    s1 += __shfl_down(s1, off, 64);
  }
  if (lane == 0) {
    out[2 * (size_t)edge]     = s0 + b2[0];
    out[2 * (size_t)edge + 1] = s1 + b2[1];
  }
}

extern "C" void kernel_launch(void* const* d_in, const int* in_sizes, int n_in,
                              void* d_out, int out_size, void* d_ws, size_t ws_size,
                              hipStream_t stream) {
  const float* feats = (const float*)d_in[0];
  const int*   edges = (const int*)d_in[1];
  const float* W1    = (const float*)d_in[2];
  const float* b1    = (const float*)d_in[3];
  const float* W2    = (const float*)d_in[4];
  const float* b2    = (const float*)d_in[5];
  float* out = (float*)d_out;

  const int n_nodes = in_sizes[0] / HID;
  const int n_edges = in_sizes[1] / 2;

  const size_t bt2_bytes = (size_t)N1 * 256 * 2;       // 256 KiB (W1^T f16)
  const size_t a_bytes   = (size_t)n_nodes * HID * 2;  // ~25.6 MB (relu'd feats f16)

  const size_t bt_bytes = (size_t)NCAT * HID * 2;      // tier-2 layout
  const size_t gh_bytes = (size_t)n_nodes * NCAT * 2;

  if (ws_size >= bt2_bytes + a_bytes) {
    f16* BT2 = (f16*)d_ws;
    f16* A   = (f16*)((char*)d_ws + bt2_bytes);
    const int total4 = n_nodes * (HID / 4);
    const int prep_total = total4 + N1 * 256;
    prep_all<<<(prep_total + 255) / 256, 256, 0, stream>>>(feats, W1, A, BT2, total4);
    const int ntiles = (n_edges + NTB - 1) / NTB;
    const int nb = ntiles < 256 ? ntiles : 256;
    fused_kernel<<<nb, 512, 0, stream>>>(A, BT2, b1, W2, b2, edges, out, n_edges, ntiles);
  } else if (ws_size >= bt_bytes + gh_bytes) {
    short* BT = (short*)d_ws;
    short* GH = (short*)((char*)d_ws + bt_bytes);
    conv_bt_bf<<<(NCAT * HID) / 256, 256, 0, stream>>>(W1, BT);
    dim3 grid((n_nodes + 63) / 64, NCAT / 128);
    gemm_bf<<<grid, 256, 0, stream>>>(feats, BT, GH, n_nodes);
    edge2_bf<<<((n_edges + 1) / 2 + 3) / 4, 256, 0, stream>>>(GH, edges, b1, W2, b2, out, n_edges);
  } else {
    slow_kernel<<<(n_edges + 3) / 4, 256, 0, stream>>>(feats, edges, W1, b1, W2, b2, out, n_edges);
  }
}